// Round 3
// baseline (442.356 us; speedup 1.0000x reference)
//
#include <hip/hip_runtime.h>

#define NK 8
#define NV 8

// Input layout: inp[b][c][h][w], C = 80, HW = 512*512 contiguous per channel.
// One float4 (4 consecutive w) per thread; all channel accesses perfectly
// coalesced (64 lanes x 16B = 1KB/instr).
//
// Round-2 post-mortem: softmax previously used reinterpret_cast<float*>(&qk[v])[c]
// (address-of + type-pun on register arrays) -> suspected SROA failure ->
// arrays in scratch. This version uses only float4 member ops; no address of
// any local is ever taken.

__device__ __forceinline__ float4 f4max(float4 a, float4 b) {
    return make_float4(fmaxf(a.x, b.x), fmaxf(a.y, b.y),
                       fmaxf(a.z, b.z), fmaxf(a.w, b.w));
}

__global__ __launch_bounds__(256) void dpa_kernel(const float* __restrict__ inp,
                                                  float* __restrict__ out) {
    constexpr int HW = 512 * 512;          // 262144
    constexpr int C = NK + NK * NV + NV;   // 80
    const float scale = 0.35355339059327373f; // 1/sqrt(8)

    int idx = blockIdx.x * blockDim.x + threadIdx.x;
    int b  = idx >> 16;          // HW/4 = 65536 float4's per batch-plane
    int s4 = idx & 65535;
    const float* pin = inp + (size_t)b * C * HW + (size_t)s4 * 4;

    float4 qk[NV];
#pragma unroll
    for (int v = 0; v < NV; ++v) qk[v] = make_float4(0.f, 0.f, 0.f, 0.f);

    // qk[v] = sum_k q[k] * K[k][v]; unroll capped to bound in-flight loads.
#pragma unroll 2
    for (int kk = 0; kk < NK; ++kk) {
        float4 qv = *reinterpret_cast<const float4*>(pin + (size_t)kk * HW);
#pragma unroll
        for (int v = 0; v < NV; ++v) {
            float4 kv = *reinterpret_cast<const float4*>(
                pin + (size_t)(NK + kk * NV + v) * HW);
            qk[v].x = fmaf(qv.x, kv.x, qk[v].x);
            qk[v].y = fmaf(qv.y, kv.y, qk[v].y);
            qk[v].z = fmaf(qv.z, kv.z, qk[v].z);
            qk[v].w = fmaf(qv.w, kv.w, qk[v].w);
        }
    }

    // scale
#pragma unroll
    for (int v = 0; v < NV; ++v) {
        qk[v].x *= scale; qk[v].y *= scale; qk[v].z *= scale; qk[v].w *= scale;
    }

    // componentwise max over v
    float4 mx = qk[0];
#pragma unroll
    for (int v = 1; v < NV; ++v) mx = f4max(mx, qk[v]);

    // exp and sum (componentwise), all member ops
    float4 sum = make_float4(0.f, 0.f, 0.f, 0.f);
#pragma unroll
    for (int v = 0; v < NV; ++v) {
        qk[v].x = __expf(qk[v].x - mx.x);
        qk[v].y = __expf(qk[v].y - mx.y);
        qk[v].z = __expf(qk[v].z - mx.z);
        qk[v].w = __expf(qk[v].w - mx.w);
        sum.x += qk[v].x; sum.y += qk[v].y; sum.z += qk[v].z; sum.w += qk[v].w;
    }
    float4 inv;
    inv.x = 1.0f / sum.x; inv.y = 1.0f / sum.y;
    inv.z = 1.0f / sum.z; inv.w = 1.0f / sum.w;

    // out[b][v][h][w] = softmax * vchan
    float* pout = out + (size_t)b * NV * HW + (size_t)s4 * 4;
#pragma unroll 4
    for (int v = 0; v < NV; ++v) {
        float4 vv = *reinterpret_cast<const float4*>(
            pin + (size_t)(NK + NK * NV + v) * HW);
        float4 r;
        r.x = qk[v].x * inv.x * vv.x;
        r.y = qk[v].y * inv.y * vv.y;
        r.z = qk[v].z * inv.z * vv.z;
        r.w = qk[v].w * inv.w * vv.w;
        *reinterpret_cast<float4*>(pout + (size_t)v * HW) = r;
    }
}

extern "C" void kernel_launch(void* const* d_in, const int* in_sizes, int n_in,
                              void* d_out, int out_size, void* d_ws, size_t ws_size,
                              hipStream_t stream) {
    const float* inp = (const float*)d_in[0];
    float* out = (float*)d_out;

    constexpr int HW = 512 * 512;
    constexpr int C = NK + NK * NV + NV; // 80
    int B = in_sizes[0] / (C * HW);      // 4

    int nThreads = B * (HW / 4);
    dim3 block(256);
    dim3 grid(nThreads / 256);
    dpa_kernel<<<grid, block, 0, stream>>>(inp, out);
}

// Round 5
// 415.250 us; speedup vs baseline: 1.0653x; 1.0653x over previous
//
#include <hip/hip_runtime.h>

#define NK 8
#define NV 8

// Input layout: inp[b][c][h][w], C = 80, HW = 512*512 contiguous per channel.
// One vec4 (4 consecutive w) per thread; all channel accesses perfectly
// coalesced (64 lanes x 16B = 1KB/instr).
//
// Round-4 fix: __builtin_nontemporal_load/store requires native clang vector
// types, not HIP_vector_type<float,4>. Use ext_vector_type(4) float.
// Round-3 analysis: dur_us (440us) is dominated by harness overhead
// (~205us d_ws poison fill + d_in restore every iteration; dpa_kernel itself
// never makes the top-5 dispatches so it is <202us). Kernel-side residual is
// 60-130us vs the 59us roofline floor (369MB @ 6.3TB/s). Non-temporal
// loads/stores (input is 335MB > 256MB L3, touched exactly once) are the
// remaining kernel-side lever.

typedef float vf4 __attribute__((ext_vector_type(4)));

__device__ __forceinline__ vf4 ntload4(const float* p) {
    return __builtin_nontemporal_load(reinterpret_cast<const vf4*>(p));
}
__device__ __forceinline__ void ntstore4(float* p, vf4 v) {
    __builtin_nontemporal_store(v, reinterpret_cast<vf4*>(p));
}

__global__ __launch_bounds__(256) void dpa_kernel(const float* __restrict__ inp,
                                                  float* __restrict__ out) {
    constexpr int HW = 512 * 512;          // 262144
    constexpr int C = NK + NK * NV + NV;   // 80
    const float scale = 0.35355339059327373f; // 1/sqrt(8)

    int idx = blockIdx.x * blockDim.x + threadIdx.x;
    int b  = idx >> 16;          // HW/4 = 65536 vec4's per batch-plane
    int s4 = idx & 65535;
    const float* pin = inp + (size_t)b * C * HW + (size_t)s4 * 4;

    vf4 qk[NV];
#pragma unroll
    for (int v = 0; v < NV; ++v) qk[v] = (vf4)(0.f);

    // qk[v] = sum_k q[k] * K[k][v]; unroll capped to bound in-flight loads.
#pragma unroll 2
    for (int kk = 0; kk < NK; ++kk) {
        vf4 qv = ntload4(pin + (size_t)kk * HW);
#pragma unroll
        for (int v = 0; v < NV; ++v) {
            vf4 kv = ntload4(pin + (size_t)(NK + kk * NV + v) * HW);
            qk[v] = qv * kv + qk[v];   // vector fma
        }
    }

    // scale
#pragma unroll
    for (int v = 0; v < NV; ++v) qk[v] *= scale;

    // componentwise max over v
    vf4 mx = qk[0];
#pragma unroll
    for (int v = 1; v < NV; ++v) {
        mx.x = fmaxf(mx.x, qk[v].x); mx.y = fmaxf(mx.y, qk[v].y);
        mx.z = fmaxf(mx.z, qk[v].z); mx.w = fmaxf(mx.w, qk[v].w);
    }

    // exp and sum (componentwise)
    vf4 sum = (vf4)(0.f);
#pragma unroll
    for (int v = 0; v < NV; ++v) {
        qk[v].x = __expf(qk[v].x - mx.x);
        qk[v].y = __expf(qk[v].y - mx.y);
        qk[v].z = __expf(qk[v].z - mx.z);
        qk[v].w = __expf(qk[v].w - mx.w);
        sum += qk[v];
    }
    vf4 inv;
    inv.x = 1.0f / sum.x; inv.y = 1.0f / sum.y;
    inv.z = 1.0f / sum.z; inv.w = 1.0f / sum.w;

    // out[b][v][h][w] = softmax * vchan
    float* pout = out + (size_t)b * NV * HW + (size_t)s4 * 4;
#pragma unroll 4
    for (int v = 0; v < NV; ++v) {
        vf4 vv = ntload4(pin + (size_t)(NK + NK * NV + v) * HW);
        ntstore4(pout + (size_t)v * HW, qk[v] * inv * vv);
    }
}

extern "C" void kernel_launch(void* const* d_in, const int* in_sizes, int n_in,
                              void* d_out, int out_size, void* d_ws, size_t ws_size,
                              hipStream_t stream) {
    const float* inp = (const float*)d_in[0];
    float* out = (float*)d_out;

    constexpr int HW = 512 * 512;
    constexpr int C = NK + NK * NV + NV; // 80
    int B = in_sizes[0] / (C * HW);      // 4

    int nThreads = B * (HW / 4);
    dim3 block(256);
    dim3 grid(nThreads / 256);
    dpa_kernel<<<grid, block, 0, stream>>>(inp, out);
}